// Round 3
// baseline (42.139 us; speedup 1.0000x reference)
//
#include <hip/hip_runtime.h>
#include <math.h>

// Problem constants
constexpr int kNB   = 16;
constexpr int kNA   = 5;
constexpr int kNC   = 80;
constexpr int kNH   = 64;
constexpr int kNW   = 64;
constexpr int kMAXT = 50;
constexpr int kCH    = 5 + kNC;          // 85
constexpr int kPLANE = kNH * kNW;        // 4096
constexpr int kCELLS_B = kNA * kPLANE;   // 20480
constexpr int kBLK  = 256;
constexpr int kBPB  = kCELLS_B / kBLK;   // 80 blocks per batch
constexpr int kGRID = kNB * kBPB;        // 1280
constexpr float kOBJ = 5.0f;

// LDS record layout (16 floats / target):
//  [0..3] x1,x2,y1,y2   [4] 0.6*garea  [5] cell(int bits)  [6..7] pad
//  [8..11] t0..t3       [12] tconf     [13] tcls           [14] owner  [15] pad
constexpr int kRECF = 16;

__device__ __forceinline__ float frcp(float x) { return __builtin_amdgcn_rcpf(x); }
__device__ __forceinline__ float fsig(float x) { return frcp(1.0f + __expf(-x)); }

__global__ __launch_bounds__(256) void k_fused(const float* __restrict__ out,
                                               const float* __restrict__ target,
                                               const float* __restrict__ anchors,
                                               float* __restrict__ partials,
                                               unsigned* __restrict__ counter,
                                               float* __restrict__ outv) {
    __shared__ __align__(16) float srec[kMAXT * kRECF];
    __shared__ int snv;
    __shared__ float wred[4];
    __shared__ int sLast;

    const int tid  = threadIdx.x;
    const int b    = blockIdx.x / kBPB;
    const int t_ce = blockIdx.x % kBPB;     // this block's CE target (if < nv)

    // ---------- Phase A: wave 0 rebuilds this batch's target records in LDS ----------
    if (tid < 64) {
        int t = tid;
        float c0 = 0.f, x = 0.f, y = 0.f, w = 0.f, h = 0.f;
        if (t < kMAXT) {
            const float* tp = target + (b * kMAXT + t) * 5;
            c0 = tp[0]; x = tp[1]; y = tp[2]; w = tp[3]; h = tp[4];
        }
        // validity prefix (cumprod of x!=0): nv = first zero-x index (<=50 since lanes>=50 have x=0)
        unsigned long long m = __ballot(x != 0.0f);
        int nv = (int)__builtin_ctzll(~m);
        if (t == 0) snv = nv;

        bool act = (t < nv);
        int cell = -1, gi = 0, gj = 0, bn = 0;
        float gx = 0, gy = 0, gw = 0, gh = 0, aw = 1.f, ah = 1.f;
        if (act) {
            gx = x * kNW; gy = y * kNH; gw = w * kNW; gh = h * kNH;
            float best = -1.0f;                       // first max wins (jnp.argmax)
            for (int n = 0; n < kNA; ++n) {
                float aw_ = anchors[2 * n], ah_ = anchors[2 * n + 1];
                float inter = fminf(gw, aw_) * fminf(gh, ah_);
                float uni = gw * gh + aw_ * ah_ - inter;
                float r = inter / uni;
                if (r > best) { best = r; bn = n; }
            }
            aw = anchors[2 * bn]; ah = anchors[2 * bn + 1];
            gi = (int)gx; gi = gi < 0 ? 0 : (gi > kNW - 1 ? kNW - 1 : gi);
            gj = (int)gy; gj = gj < 0 ? 0 : (gj > kNH - 1 ? kNH - 1 : gj);
            cell = bn * kPLANE + gj * kNW + gi;
        }
        // owner = last target writing this cell (scatter last-write-wins), via shuffles
        bool owner = act;
        for (int t2 = 0; t2 < kMAXT; ++t2) {          // nv uniform, but keep trip uniform anyway
            int c2 = __shfl(cell, t2, 64);
            if (act && t2 > t && t2 < nv && c2 == cell) owner = false;
        }
        if (act) {
            const float* ob = out + ((size_t)(b * kNA + bn) * kCH) * kPLANE + gj * kNW + gi;
            float px = fsig(ob[0]) + (float)gi;
            float py = fsig(ob[kPLANE]) + (float)gj;
            float pw = __expf(ob[2 * kPLANE]) * aw;
            float ph = __expf(ob[3 * kPLANE]) * ah;
            float cw  = fminf(gx + 0.5f * gw, px + 0.5f * pw) - fmaxf(gx - 0.5f * gw, px - 0.5f * pw);
            float chh = fminf(gy + 0.5f * gh, py + 0.5f * ph) - fmaxf(gy - 0.5f * gh, py - 0.5f * ph);
            float inter = fmaxf(cw, 0.f) * fmaxf(chh, 0.f);
            float uni = gw * gh + pw * ph - inter;
            float iou = (inter > 0.f) ? inter / uni : 0.f;

            float* r = srec + t * kRECF;
            r[0]  = gx - 0.5f * gw;  r[1]  = gx + 0.5f * gw;
            r[2]  = gy - 0.5f * gh;  r[3]  = gy + 0.5f * gh;
            r[4]  = 0.6f * gw * gh;  r[5]  = __int_as_float(cell);
            r[6]  = 0.f;             r[7]  = 0.f;
            r[8]  = gx - (float)gi;  r[9]  = gy - (float)gj;
            r[10] = __logf(gw / aw); r[11] = __logf(gh / ah);
            r[12] = iou;             r[13] = c0;
            r[14] = owner ? 1.f : 0.f; r[15] = 0.f;
        }
    }
    __syncthreads();
    const int nv = snv;

    // ---------- Phase B: issue CE loads early (wave 0, one owner-target per block) ----------
    float ceV0 = 0.f, ceV1 = -INFINITY, ceLt = 0.f;
    bool doCE = false;
    if (tid < 64 && t_ce < nv && srec[t_ce * kRECF + 14] != 0.f) {
        doCE = true;
        int cell = __float_as_int(srec[t_ce * kRECF + 5]);
        int bn = cell >> 12, pix = cell & (kPLANE - 1);
        int tcls = (int)srec[t_ce * kRECF + 13];
        const float* lg = out + ((size_t)(b * kNA + bn) * kCH + 5) * kPLANE + pix;
        ceV0 = lg[(size_t)tid * kPLANE];
        if (tid < kNC - 64) ceV1 = lg[(size_t)(64 + tid) * kPLANE];
        ceLt = lg[(size_t)tcls * kPLANE];
    }

    // ---------- Phase C: per-cell loss ----------
    int within = blockIdx.x % kBPB * kBLK + tid;      // 0..20479 within batch
    within += 0; // (t_ce*kBLK+tid)
    int a = (t_ce * kBLK + tid) / kPLANE;
    int remp = (t_ce * kBLK + tid) & (kPLANE - 1);
    int i = remp & (kNW - 1), j = remp >> 6;

    const float* ob = out + ((size_t)(b * kNA + a) * kCH) * kPLANE + remp;
    float tx   = fsig(ob[0]);
    float ty   = fsig(ob[kPLANE]);
    float tw   = ob[2 * kPLANE];
    float th   = ob[3 * kPLANE];
    float conf = fsig(ob[4 * kPLANE]);

    float aw = anchors[2 * a], ah = anchors[2 * a + 1];
    float pw = __expf(tw) * aw, ph = __expf(th) * ah;
    float px = tx + (float)i, py = ty + (float)j;
    float px1 = px - 0.5f * pw, px2 = px + 0.5f * pw;
    float py1 = py - 0.5f * ph, py2 = py + 0.5f * ph;
    float p06 = 0.6f * pw * ph;
    int mycell = a * kPLANE + remp;

    // divide-free: iou > 0.6  <=>  1.6*inter > 0.6*(garea+parea)
    float flag = -1.f;
    int match = -1;                                   // last matching t wins
    for (int t = 0; t < nv; ++t) {
        const float4 bx = *reinterpret_cast<const float4*>(srec + t * kRECF);
        const float2 gc = *reinterpret_cast<const float2*>(srec + t * kRECF + 4);
        float cw  = fminf(bx.y, px2) - fmaxf(bx.x, px1);
        float chh = fminf(bx.w, py2) - fmaxf(bx.z, py1);
        float inter = fmaxf(cw, 0.f) * fmaxf(chh, 0.f);
        flag = fmaxf(flag, fmaf(1.6f, inter, -(gc.x + p06)));
        match = (__float_as_int(gc.y) == mycell) ? t : match;
    }

    float t0 = 0.5f, t1 = 0.5f, t2 = 0.f, t3 = 0.f, tconf = 0.f, cmask;
    if (match >= 0) {
        const float4 tt = *reinterpret_cast<const float4*>(srec + match * kRECF + 8);
        t0 = tt.x; t1 = tt.y; t2 = tt.z; t3 = tt.w;
        tconf = srec[match * kRECF + 12];
        cmask = kOBJ;
    } else {
        cmask = (flag > 0.f) ? 0.f : 1.f;
    }

    float dx = tx - t0, dy = ty - t1, dw = tw - t2, dh = th - t3, dc = conf - tconf;
    float loss = 0.5f * (dx * dx + dy * dy + dw * dw + dh * dh)
               + 0.5f * cmask * dc * dc;

    // ---------- Phase D: finish CE (wave-uniform branch within wave 0) ----------
    if (doCE) {
        float mx = fmaxf(ceV0, ceV1);
        #pragma unroll
        for (int off = 32; off > 0; off >>= 1) mx = fmaxf(mx, __shfl_xor(mx, off, 64));
        float s = __expf(ceV0 - mx) + ((tid < kNC - 64) ? __expf(ceV1 - mx) : 0.f);
        #pragma unroll
        for (int off = 32; off > 0; off >>= 1) s += __shfl_xor(s, off, 64);
        if (tid == 0) loss += __logf(s) + mx - ceLt;
    }

    // ---------- Phase E: block reduction + last-block-done final sum ----------
    #pragma unroll
    for (int off = 32; off > 0; off >>= 1) loss += __shfl_down(loss, off, 64);
    if ((tid & 63) == 0) wred[tid >> 6] = loss;
    __syncthreads();
    if (tid == 0) {
        partials[blockIdx.x] = wred[0] + wred[1] + wred[2] + wred[3];
        __threadfence();
        unsigned ticket = atomicAdd(counter, 1u);
        sLast = (ticket == kGRID - 1) ? 1 : 0;
    }
    __syncthreads();
    if (sLast) {
        // deterministic: one block, fixed-order read of all partials
        volatile const float* vp = partials;
        __shared__ float red[256];
        float s = 0.f;
        for (int k = tid; k < kGRID; k += 256) s += vp[k];
        red[tid] = s;
        __syncthreads();
        for (int off = 128; off > 0; off >>= 1) {
            if (tid < off) red[tid] += red[tid + off];
            __syncthreads();
        }
        if (tid == 0) outv[0] = red[0];
    }
}

extern "C" void kernel_launch(void* const* d_in, const int* in_sizes, int n_in,
                              void* d_out, int out_size, void* d_ws, size_t ws_size,
                              hipStream_t stream) {
    const float* output  = (const float*)d_in[0];
    const float* target  = (const float*)d_in[1];
    const float* anchors = (const float*)d_in[2];

    unsigned* counter = (unsigned*)d_ws;             // 1 uint (zeroed each call)
    float* partials = (float*)d_ws + 16;             // 1280 floats, 64B-aligned

    hipMemsetAsync(counter, 0, sizeof(unsigned), stream);
    k_fused<<<kGRID, kBLK, 0, stream>>>(output, target, anchors, partials, counter, (float*)d_out);
}

// Round 4
// 17.134 us; speedup vs baseline: 2.4594x; 2.4594x over previous
//
#include <hip/hip_runtime.h>
#include <math.h>

// Problem constants
constexpr int kNB   = 16;
constexpr int kNA   = 5;
constexpr int kNC   = 80;
constexpr int kNH   = 64;
constexpr int kNW   = 64;
constexpr int kMAXT = 50;
constexpr int kCH    = 5 + kNC;          // 85
constexpr int kPLANE = kNH * kNW;        // 4096
constexpr int kCELLS_B = kNA * kPLANE;   // 20480
constexpr int kBLK  = 256;
constexpr int kBPB  = kCELLS_B / kBLK;   // 80 blocks per batch
constexpr int kGRID = kNB * kBPB;        // 1280
constexpr float kOBJ = 5.0f;

// LDS record layout (16 floats / target):
//  [0..3] x1,x2,y1,y2   [4] 0.6*garea  [5] cell(int bits)  [6..7] pad
//  [8..11] t0..t3       [12] tconf     [13] tcls           [14] owner  [15] pad
constexpr int kRECF = 16;

__device__ __forceinline__ float frcp(float x) { return __builtin_amdgcn_rcpf(x); }
__device__ __forceinline__ float fsig(float x) { return frcp(1.0f + __expf(-x)); }

__global__ __launch_bounds__(256) void k_fused(const float* __restrict__ out,
                                               const float* __restrict__ target,
                                               const float* __restrict__ anchors,
                                               float* __restrict__ partials) {
    __shared__ __align__(16) float srec[kMAXT * kRECF];
    __shared__ int snv;
    __shared__ float wred[4];

    const int tid  = threadIdx.x;
    const int b    = blockIdx.x / kBPB;
    const int t_ce = blockIdx.x % kBPB;     // this block's CE target (if < nv)

    // ---------- Phase A: wave 0 rebuilds this batch's target records in LDS ----------
    if (tid < 64) {
        int t = tid;
        float c0 = 0.f, x = 0.f, y = 0.f, w = 0.f, h = 0.f;
        if (t < kMAXT) {
            const float* tp = target + (b * kMAXT + t) * 5;
            c0 = tp[0]; x = tp[1]; y = tp[2]; w = tp[3]; h = tp[4];
        }
        // validity prefix (cumprod of x!=0): nv = first zero-x index (<=50; lanes>=50 have x=0)
        unsigned long long m = __ballot(x != 0.0f);
        int nv = (int)__builtin_ctzll(~m);
        if (t == 0) snv = nv;

        bool act = (t < nv);
        int cell = -1, gi = 0, gj = 0, bn = 0;
        float gx = 0, gy = 0, gw = 0, gh = 0, aw = 1.f, ah = 1.f;
        if (act) {
            gx = x * kNW; gy = y * kNH; gw = w * kNW; gh = h * kNH;
            float best = -1.0f;                       // first max wins (jnp.argmax)
            for (int n = 0; n < kNA; ++n) {
                float aw_ = anchors[2 * n], ah_ = anchors[2 * n + 1];
                float inter = fminf(gw, aw_) * fminf(gh, ah_);
                float uni = gw * gh + aw_ * ah_ - inter;
                float r = inter / uni;
                if (r > best) { best = r; bn = n; }
            }
            aw = anchors[2 * bn]; ah = anchors[2 * bn + 1];
            gi = (int)gx; gi = gi < 0 ? 0 : (gi > kNW - 1 ? kNW - 1 : gi);
            gj = (int)gy; gj = gj < 0 ? 0 : (gj > kNH - 1 ? kNH - 1 : gj);
            cell = bn * kPLANE + gj * kNW + gi;
        }
        // owner = last target writing this cell (scatter last-write-wins), via shuffles
        bool owner = act;
        for (int t2 = 0; t2 < kMAXT; ++t2) {
            int c2 = __shfl(cell, t2, 64);
            if (act && t2 > t && t2 < nv && c2 == cell) owner = false;
        }
        if (act) {
            const float* ob = out + ((size_t)(b * kNA + bn) * kCH) * kPLANE + gj * kNW + gi;
            float px = fsig(ob[0]) + (float)gi;
            float py = fsig(ob[kPLANE]) + (float)gj;
            float pw = __expf(ob[2 * kPLANE]) * aw;
            float ph = __expf(ob[3 * kPLANE]) * ah;
            float cw  = fminf(gx + 0.5f * gw, px + 0.5f * pw) - fmaxf(gx - 0.5f * gw, px - 0.5f * pw);
            float chh = fminf(gy + 0.5f * gh, py + 0.5f * ph) - fmaxf(gy - 0.5f * gh, py - 0.5f * ph);
            float inter = fmaxf(cw, 0.f) * fmaxf(chh, 0.f);
            float uni = gw * gh + pw * ph - inter;
            float iou = (inter > 0.f) ? inter / uni : 0.f;

            float* r = srec + t * kRECF;
            r[0]  = gx - 0.5f * gw;  r[1]  = gx + 0.5f * gw;
            r[2]  = gy - 0.5f * gh;  r[3]  = gy + 0.5f * gh;
            r[4]  = 0.6f * gw * gh;  r[5]  = __int_as_float(cell);
            r[6]  = 0.f;             r[7]  = 0.f;
            r[8]  = gx - (float)gi;  r[9]  = gy - (float)gj;
            r[10] = __logf(gw / aw); r[11] = __logf(gh / ah);
            r[12] = iou;             r[13] = c0;
            r[14] = owner ? 1.f : 0.f; r[15] = 0.f;
        }
    }
    __syncthreads();
    const int nv = snv;

    // ---------- Phase B: issue CE loads early (wave 0, one owner-target per block) ----------
    float ceV0 = 0.f, ceV1 = -INFINITY, ceLt = 0.f;
    bool doCE = false;
    if (tid < 64 && t_ce < nv && srec[t_ce * kRECF + 14] != 0.f) {
        doCE = true;
        int cell = __float_as_int(srec[t_ce * kRECF + 5]);
        int bn = cell >> 12, pix = cell & (kPLANE - 1);
        int tcls = (int)srec[t_ce * kRECF + 13];
        const float* lg = out + ((size_t)(b * kNA + bn) * kCH + 5) * kPLANE + pix;
        ceV0 = lg[(size_t)tid * kPLANE];
        if (tid < kNC - 64) ceV1 = lg[(size_t)(64 + tid) * kPLANE];
        ceLt = lg[(size_t)tcls * kPLANE];
    }

    // ---------- Phase C: per-cell loss ----------
    int a = (t_ce * kBLK + tid) / kPLANE;
    int remp = (t_ce * kBLK + tid) & (kPLANE - 1);
    int i = remp & (kNW - 1), j = remp >> 6;

    const float* ob = out + ((size_t)(b * kNA + a) * kCH) * kPLANE + remp;
    float tx   = fsig(ob[0]);
    float ty   = fsig(ob[kPLANE]);
    float tw   = ob[2 * kPLANE];
    float th   = ob[3 * kPLANE];
    float conf = fsig(ob[4 * kPLANE]);

    float aw = anchors[2 * a], ah = anchors[2 * a + 1];
    float pw = __expf(tw) * aw, ph = __expf(th) * ah;
    float px = tx + (float)i, py = ty + (float)j;
    float px1 = px - 0.5f * pw, px2 = px + 0.5f * pw;
    float py1 = py - 0.5f * ph, py2 = py + 0.5f * ph;
    float p06 = 0.6f * pw * ph;
    int mycell = a * kPLANE + remp;

    // divide-free: iou > 0.6  <=>  1.6*inter > 0.6*(garea+parea)
    float flag = -1.f;
    int match = -1;                                   // last matching t wins
    for (int t = 0; t < nv; ++t) {
        const float4 bx = *reinterpret_cast<const float4*>(srec + t * kRECF);
        const float2 gc = *reinterpret_cast<const float2*>(srec + t * kRECF + 4);
        float cw  = fminf(bx.y, px2) - fmaxf(bx.x, px1);
        float chh = fminf(bx.w, py2) - fmaxf(bx.z, py1);
        float inter = fmaxf(cw, 0.f) * fmaxf(chh, 0.f);
        flag = fmaxf(flag, fmaf(1.6f, inter, -(gc.x + p06)));
        match = (__float_as_int(gc.y) == mycell) ? t : match;
    }

    float t0 = 0.5f, t1 = 0.5f, t2 = 0.f, t3 = 0.f, tconf = 0.f, cmask;
    if (match >= 0) {
        const float4 tt = *reinterpret_cast<const float4*>(srec + match * kRECF + 8);
        t0 = tt.x; t1 = tt.y; t2 = tt.z; t3 = tt.w;
        tconf = srec[match * kRECF + 12];
        cmask = kOBJ;
    } else {
        cmask = (flag > 0.f) ? 0.f : 1.f;
    }

    float dx = tx - t0, dy = ty - t1, dw = tw - t2, dh = th - t3, dc = conf - tconf;
    float loss = 0.5f * (dx * dx + dy * dy + dw * dw + dh * dh)
               + 0.5f * cmask * dc * dc;

    // ---------- Phase D: finish CE (wave-uniform branch within wave 0) ----------
    if (doCE) {
        float mx = fmaxf(ceV0, ceV1);
        #pragma unroll
        for (int off = 32; off > 0; off >>= 1) mx = fmaxf(mx, __shfl_xor(mx, off, 64));
        float s = __expf(ceV0 - mx) + ((tid < kNC - 64) ? __expf(ceV1 - mx) : 0.f);
        #pragma unroll
        for (int off = 32; off > 0; off >>= 1) s += __shfl_xor(s, off, 64);
        if (tid == 0) loss += __logf(s) + mx - ceLt;
    }

    // ---------- Phase E: block reduction -> one partial per block ----------
    #pragma unroll
    for (int off = 32; off > 0; off >>= 1) loss += __shfl_down(loss, off, 64);
    if ((tid & 63) == 0) wred[tid >> 6] = loss;
    __syncthreads();
    if (tid == 0)
        partials[blockIdx.x] = wred[0] + wred[1] + wred[2] + wred[3];
}

// -------------------- Kernel 2: deterministic final sum --------------------
__global__ __launch_bounds__(256) void k_final(const float* __restrict__ partials,
                                               float* __restrict__ outv) {
    __shared__ float red[256];
    float s = 0.f;
    for (int k = threadIdx.x; k < kGRID; k += 256) s += partials[k];
    red[threadIdx.x] = s;
    __syncthreads();
    for (int off = 128; off > 0; off >>= 1) {
        if (threadIdx.x < off) red[threadIdx.x] += red[threadIdx.x + off];
        __syncthreads();
    }
    if (threadIdx.x == 0) outv[0] = red[0];
}

extern "C" void kernel_launch(void* const* d_in, const int* in_sizes, int n_in,
                              void* d_out, int out_size, void* d_ws, size_t ws_size,
                              hipStream_t stream) {
    const float* output  = (const float*)d_in[0];
    const float* target  = (const float*)d_in[1];
    const float* anchors = (const float*)d_in[2];

    float* partials = (float*)d_ws;                  // 1280 floats

    k_fused<<<kGRID, kBLK, 0, stream>>>(output, target, anchors, partials);
    k_final<<<1, 256, 0, stream>>>(partials, (float*)d_out);
}

// Round 5
// 16.941 us; speedup vs baseline: 2.4873x; 1.0114x over previous
//
#include <hip/hip_runtime.h>
#include <math.h>

// Problem constants
constexpr int kNB   = 16;
constexpr int kNA   = 5;
constexpr int kNC   = 80;
constexpr int kNH   = 64;
constexpr int kNW   = 64;
constexpr int kMAXT = 50;
constexpr int kCH    = 5 + kNC;          // 85
constexpr int kPLANE = kNH * kNW;        // 4096
constexpr int kCELLS_B = kNA * kPLANE;   // 20480
constexpr int kBLK  = 256;
constexpr int kBPB  = kCELLS_B / kBLK;   // 80 blocks per batch
constexpr int kGRID = kNB * kBPB;        // 1280
constexpr float kOBJ = 5.0f;

// LDS record layout (16 floats / target):
//  [0..3] x1,x2,y1,y2   [4] 0.6*garea  [5] cell(int bits)
//  [8..11] t0..t3       [12] tconf     [13] tcls
constexpr int kRECF = 16;

__device__ __forceinline__ float frcp(float x) { return __builtin_amdgcn_rcpf(x); }
__device__ __forceinline__ float fsig(float x) { return frcp(1.0f + __expf(-x)); }

__global__ __launch_bounds__(256) void k_fused(const float* __restrict__ out,
                                               const float* __restrict__ target,
                                               const float* __restrict__ anchors,
                                               float* __restrict__ partials) {
    __shared__ __align__(16) float srec[kMAXT * kRECF];
    __shared__ int snv;
    __shared__ float wred[4];

    const int tid  = threadIdx.x;
    const int wave = tid >> 6;
    const int lane = tid & 63;
    const int b    = blockIdx.x / kBPB;
    const int t_ce = blockIdx.x % kBPB;       // this block's CE target (if < nv)

    // ---------- Phase 0: EVERY thread issues its Phase-C loads first (hide HBM latency) ----
    const int cidx = t_ce * kBLK + tid;       // within-batch cell 0..20479
    const int a    = cidx / kPLANE;
    const int remp = cidx & (kPLANE - 1);
    const int i    = remp & (kNW - 1), j = remp >> 6;
    const float* ob = out + ((size_t)(b * kNA + a) * kCH) * kPLANE + remp;
    float o0 = ob[0];
    float o1 = ob[kPLANE];
    float o2 = ob[2 * kPLANE];
    float o3 = ob[3 * kPLANE];
    float o4 = ob[4 * kPLANE];

    // ---------- Phase A (wave 0): build target records  |  CE-prep (wave 1) ----------
    float ceV0 = 0.f, ceV1 = -INFINITY, ceLt = 0.f;
    bool doCE = false;

    if (wave == 0) {
        int t = lane;
        float c0 = 0.f, x = 0.f, y = 0.f, w = 0.f, h = 0.f;
        if (t < kMAXT) {
            const float* tp = target + (b * kMAXT + t) * 5;
            c0 = tp[0]; x = tp[1]; y = tp[2]; w = tp[3]; h = tp[4];
        }
        unsigned long long m = __ballot(x != 0.0f);   // validity prefix
        int nv = (int)__builtin_ctzll(~m);
        if (t == 0) snv = nv;

        if (t < nv) {
            float gx = x * kNW, gy = y * kNH, gw = w * kNW, gh = h * kNH;
            int bn = 0; float best = -1.0f;            // first max wins
            for (int n = 0; n < kNA; ++n) {
                float aw_ = anchors[2 * n], ah_ = anchors[2 * n + 1];
                float inter = fminf(gw, aw_) * fminf(gh, ah_);
                float uni = gw * gh + aw_ * ah_ - inter;
                float r = inter / uni;
                if (r > best) { best = r; bn = n; }
            }
            float aw = anchors[2 * bn], ah = anchors[2 * bn + 1];
            int gi = (int)gx; gi = gi < 0 ? 0 : (gi > kNW - 1 ? kNW - 1 : gi);
            int gj = (int)gy; gj = gj < 0 ? 0 : (gj > kNH - 1 ? kNH - 1 : gj);
            int cell = bn * kPLANE + gj * kNW + gi;

            const float* mb = out + ((size_t)(b * kNA + bn) * kCH) * kPLANE + gj * kNW + gi;
            float px = fsig(mb[0]) + (float)gi;
            float py = fsig(mb[kPLANE]) + (float)gj;
            float pw = __expf(mb[2 * kPLANE]) * aw;
            float ph = __expf(mb[3 * kPLANE]) * ah;
            float cw  = fminf(gx + 0.5f * gw, px + 0.5f * pw) - fmaxf(gx - 0.5f * gw, px - 0.5f * pw);
            float chh = fminf(gy + 0.5f * gh, py + 0.5f * ph) - fmaxf(gy - 0.5f * gh, py - 0.5f * ph);
            float inter = fmaxf(cw, 0.f) * fmaxf(chh, 0.f);
            float uni = gw * gh + pw * ph - inter;
            float iou = (inter > 0.f) ? inter / uni : 0.f;

            float* r = srec + t * kRECF;
            r[0]  = gx - 0.5f * gw;  r[1]  = gx + 0.5f * gw;
            r[2]  = gy - 0.5f * gh;  r[3]  = gy + 0.5f * gh;
            r[4]  = 0.6f * gw * gh;  r[5]  = __int_as_float(cell);
            r[8]  = gx - (float)gi;  r[9]  = gy - (float)gj;
            r[10] = __logf(gw / aw); r[11] = __logf(gh / ah);
            r[12] = iou;             r[13] = c0;
        }
    } else if (wave == 1) {
        // recompute per-target cells (cheap), owner check via one ballot, issue CE loads
        int t = lane;
        float c0 = 0.f, x = 0.f, y = 0.f, w = 0.f, h = 0.f;
        if (t < kMAXT) {
            const float* tp = target + (b * kMAXT + t) * 5;
            c0 = tp[0]; x = tp[1]; y = tp[2]; w = tp[3]; h = tp[4];
        }
        unsigned long long m = __ballot(x != 0.0f);
        int nv = (int)__builtin_ctzll(~m);

        int cell = -1;
        if (t < nv) {
            float gx = x * kNW, gy = y * kNH, gw = w * kNW, gh = h * kNH;
            int bn = 0; float best = -1.0f;
            for (int n = 0; n < kNA; ++n) {
                float aw_ = anchors[2 * n], ah_ = anchors[2 * n + 1];
                float inter = fminf(gw, aw_) * fminf(gh, ah_);
                float uni = gw * gh + aw_ * ah_ - inter;
                float r = inter / uni;
                if (r > best) { best = r; bn = n; }
            }
            int gi = (int)gx; gi = gi < 0 ? 0 : (gi > kNW - 1 ? kNW - 1 : gi);
            int gj = (int)gy; gj = gj < 0 ? 0 : (gj > kNH - 1 ? kNH - 1 : gj);
            cell = bn * kPLANE + gj * kNW + gi;
        }
        int   cellT = __shfl(cell, t_ce & 63, 64);
        float c0T   = __shfl(c0,   t_ce & 63, 64);
        // owner = no later valid target maps to the same cell (scatter last-write-wins)
        unsigned long long dup = __ballot(t > t_ce && cell == cellT && cell >= 0);
        doCE = (t_ce < nv) && (dup == 0ull);
        if (doCE) {
            int bn = cellT >> 12, pix = cellT & (kPLANE - 1);
            int tcls = (int)c0T;
            const float* lg = out + ((size_t)(b * kNA + bn) * kCH + 5) * kPLANE + pix;
            ceV0 = lg[(size_t)lane * kPLANE];
            if (lane < kNC - 64) ceV1 = lg[(size_t)(64 + lane) * kPLANE];
            ceLt = lg[(size_t)tcls * kPLANE];
        }
    }
    __syncthreads();
    const int nv = snv;

    // ---------- Phase C: per-cell loss (loads o0..o4 already in flight/registers) -------
    float tx   = fsig(o0);
    float ty   = fsig(o1);
    float tw   = o2;
    float th   = o3;
    float conf = fsig(o4);

    float aw = anchors[2 * a], ah = anchors[2 * a + 1];
    float pw = __expf(tw) * aw, ph = __expf(th) * ah;
    float px = tx + (float)i, py = ty + (float)j;
    float px1 = px - 0.5f * pw, px2 = px + 0.5f * pw;
    float py1 = py - 0.5f * ph, py2 = py + 0.5f * ph;
    float p06 = 0.6f * pw * ph;
    int mycell = a * kPLANE + remp;

    // iou > 0.6  <=>  max_t(1.6*inter - 0.6*garea) > 0.6*parea
    float flag = -INFINITY;
    int match = -1;                                   // last matching t wins
    for (int t = 0; t < nv; ++t) {
        const float4 bx = *reinterpret_cast<const float4*>(srec + t * kRECF);
        const float2 gc = *reinterpret_cast<const float2*>(srec + t * kRECF + 4);
        float cw  = fminf(bx.y, px2) - fmaxf(bx.x, px1);
        float chh = fminf(bx.w, py2) - fmaxf(bx.z, py1);
        float inter = fmaxf(cw, 0.f) * fmaxf(chh, 0.f);
        flag = fmaxf(flag, fmaf(1.6f, inter, -gc.x));
        match = (__float_as_int(gc.y) == mycell) ? t : match;
    }

    float t0 = 0.5f, t1 = 0.5f, t2 = 0.f, t3 = 0.f, tconf = 0.f, cmask;
    if (match >= 0) {
        const float4 tt = *reinterpret_cast<const float4*>(srec + match * kRECF + 8);
        t0 = tt.x; t1 = tt.y; t2 = tt.z; t3 = tt.w;
        tconf = srec[match * kRECF + 12];
        cmask = kOBJ;
    } else {
        cmask = (flag > p06) ? 0.f : 1.f;
    }

    float dx = tx - t0, dy = ty - t1, dw = tw - t2, dh = th - t3, dc = conf - tconf;
    float loss = 0.5f * (dx * dx + dy * dy + dw * dw + dh * dh)
               + 0.5f * cmask * dc * dc;

    // ---------- Phase D: finish CE on wave 1 (wave-uniform) ----------
    if (wave == 1 && doCE) {
        float mx = fmaxf(ceV0, ceV1);
        #pragma unroll
        for (int off = 32; off > 0; off >>= 1) mx = fmaxf(mx, __shfl_xor(mx, off, 64));
        float s = __expf(ceV0 - mx) + ((lane < kNC - 64) ? __expf(ceV1 - mx) : 0.f);
        #pragma unroll
        for (int off = 32; off > 0; off >>= 1) s += __shfl_xor(s, off, 64);
        if (lane == 0) loss += __logf(s) + mx - ceLt;
    }

    // ---------- Phase E: block reduction -> one partial per block ----------
    #pragma unroll
    for (int off = 32; off > 0; off >>= 1) loss += __shfl_down(loss, off, 64);
    if (lane == 0) wred[wave] = loss;
    __syncthreads();
    if (tid == 0)
        partials[blockIdx.x] = wred[0] + wred[1] + wred[2] + wred[3];
}

// -------------------- Kernel 2: deterministic final sum (one wave) --------------------
__global__ __launch_bounds__(64) void k_final(const float* __restrict__ partials,
                                              float* __restrict__ outv) {
    float s = 0.f;
    for (int k = threadIdx.x; k < kGRID; k += 64) s += partials[k];
    #pragma unroll
    for (int off = 32; off > 0; off >>= 1) s += __shfl_xor(s, off, 64);
    if (threadIdx.x == 0) outv[0] = s;
}

extern "C" void kernel_launch(void* const* d_in, const int* in_sizes, int n_in,
                              void* d_out, int out_size, void* d_ws, size_t ws_size,
                              hipStream_t stream) {
    const float* output  = (const float*)d_in[0];
    const float* target  = (const float*)d_in[1];
    const float* anchors = (const float*)d_in[2];

    float* partials = (float*)d_ws;                  // 1280 floats

    k_fused<<<kGRID, kBLK, 0, stream>>>(output, target, anchors, partials);
    k_final<<<1, 64, 0, stream>>>(partials, (float*)d_out);
}

// Round 6
// 15.721 us; speedup vs baseline: 2.6805x; 1.0777x over previous
//
#include <hip/hip_runtime.h>
#include <math.h>

// Problem constants
constexpr int kNB   = 16;
constexpr int kNA   = 5;
constexpr int kNC   = 80;
constexpr int kNH   = 64;
constexpr int kNW   = 64;
constexpr int kMAXT = 50;
constexpr int kCH    = 5 + kNC;          // 85
constexpr int kPLANE = kNH * kNW;        // 4096
constexpr int kCELLS_B = kNA * kPLANE;   // 20480
constexpr int kBLK  = 1024;              // 16 waves
constexpr int kBPB  = kCELLS_B / kBLK;   // 20 blocks per batch
constexpr int kGRID = kNB * kBPB;        // 320
constexpr float kOBJ = 5.0f;

// LDS record layout (16 floats / target):
//  [0..3] x1,x2,y1,y2   [4] 0.6*garea  [5] cell(int bits)
//  [8..11] t0..t3       [12] tconf     [13] tcls
constexpr int kRECF = 16;

__device__ __forceinline__ float frcp(float x) { return __builtin_amdgcn_rcpf(x); }
__device__ __forceinline__ float fsig(float x) { return frcp(1.0f + __expf(-x)); }

__global__ __launch_bounds__(1024) void k_fused(const float* __restrict__ out,
                                                const float* __restrict__ target,
                                                const float* __restrict__ anchors,
                                                float* __restrict__ partials) {
    __shared__ __align__(16) float srec[kMAXT * kRECF];
    __shared__ int snv;
    __shared__ float wred[16];

    const int tid  = threadIdx.x;
    const int wave = tid >> 6;
    const int lane = tid & 63;
    const int b    = blockIdx.x / kBPB;
    const int blkb = blockIdx.x % kBPB;      // 0..19 within batch

    // ---------- Phase 0: every thread issues its Phase-C channel loads first ----------
    const int cidx = blkb * kBLK + tid;      // within-batch cell 0..20479
    const int a    = cidx / kPLANE;          // block-uniform (1024 cells within one plane)
    const int remp = cidx & (kPLANE - 1);
    const int i    = remp & (kNW - 1), j = remp >> 6;
    const float* ob = out + ((size_t)(b * kNA + a) * kCH) * kPLANE + remp;
    float o0 = ob[0];
    float o1 = ob[kPLANE];
    float o2 = ob[2 * kPLANE];
    float o3 = ob[3 * kPLANE];
    float o4 = ob[4 * kPLANE];

    // ---------- Phase A: wave 0 builds records; waves 1-3 prep CE (3 targets/block) ----
    float ceV0 = 0.f, ceV1 = -INFINITY, ceLt = 0.f;
    bool doCE = false;

    if (wave == 0) {
        int t = lane;
        float c0 = 0.f, x = 0.f, y = 0.f, w = 0.f, h = 0.f;
        if (t < kMAXT) {
            const float* tp = target + (b * kMAXT + t) * 5;
            c0 = tp[0]; x = tp[1]; y = tp[2]; w = tp[3]; h = tp[4];
        }
        unsigned long long m = __ballot(x != 0.0f);   // validity prefix (cumprod of x!=0)
        int nv = (int)__builtin_ctzll(~m);
        if (t == 0) snv = nv;

        if (t < nv) {
            float gx = x * kNW, gy = y * kNH, gw = w * kNW, gh = h * kNH;
            int bn = 0; float best = -1.0f;            // first max wins (jnp.argmax)
            for (int n = 0; n < kNA; ++n) {
                float aw_ = anchors[2 * n], ah_ = anchors[2 * n + 1];
                float inter = fminf(gw, aw_) * fminf(gh, ah_);
                float uni = gw * gh + aw_ * ah_ - inter;
                float r = inter / uni;
                if (r > best) { best = r; bn = n; }
            }
            float aw = anchors[2 * bn], ah = anchors[2 * bn + 1];
            int gi = (int)gx; gi = gi < 0 ? 0 : (gi > kNW - 1 ? kNW - 1 : gi);
            int gj = (int)gy; gj = gj < 0 ? 0 : (gj > kNH - 1 ? kNH - 1 : gj);
            int cell = bn * kPLANE + gj * kNW + gi;

            const float* mb = out + ((size_t)(b * kNA + bn) * kCH) * kPLANE + gj * kNW + gi;
            float px = fsig(mb[0]) + (float)gi;
            float py = fsig(mb[kPLANE]) + (float)gj;
            float pw = __expf(mb[2 * kPLANE]) * aw;
            float ph = __expf(mb[3 * kPLANE]) * ah;
            float cw  = fminf(gx + 0.5f * gw, px + 0.5f * pw) - fmaxf(gx - 0.5f * gw, px - 0.5f * pw);
            float chh = fminf(gy + 0.5f * gh, py + 0.5f * ph) - fmaxf(gy - 0.5f * gh, py - 0.5f * ph);
            float inter = fmaxf(cw, 0.f) * fmaxf(chh, 0.f);
            float uni = gw * gh + pw * ph - inter;
            float iou = (inter > 0.f) ? inter / uni : 0.f;

            float* r = srec + t * kRECF;
            r[0]  = gx - 0.5f * gw;  r[1]  = gx + 0.5f * gw;
            r[2]  = gy - 0.5f * gh;  r[3]  = gy + 0.5f * gh;
            r[4]  = 0.6f * gw * gh;  r[5]  = __int_as_float(cell);
            r[8]  = gx - (float)gi;  r[9]  = gy - (float)gj;
            r[10] = __logf(gw / aw); r[11] = __logf(gh / ah);
            r[12] = iou;             r[13] = c0;
        }
    } else if (wave <= 3) {
        // CE prep: this wave owns target t_ce (if valid & owner). One ballot owner-check.
        const int t_ce = blkb + kBPB * (wave - 1);    // 0..59 covers all 50
        int t = lane;
        float c0 = 0.f, x = 0.f, y = 0.f, w = 0.f, h = 0.f;
        if (t < kMAXT) {
            const float* tp = target + (b * kMAXT + t) * 5;
            c0 = tp[0]; x = tp[1]; y = tp[2]; w = tp[3]; h = tp[4];
        }
        unsigned long long m = __ballot(x != 0.0f);
        int nv = (int)__builtin_ctzll(~m);

        int cell = -1;
        if (t < nv) {
            float gx = x * kNW, gy = y * kNH, gw = w * kNW, gh = h * kNH;
            int bn = 0; float best = -1.0f;
            for (int n = 0; n < kNA; ++n) {
                float aw_ = anchors[2 * n], ah_ = anchors[2 * n + 1];
                float inter = fminf(gw, aw_) * fminf(gh, ah_);
                float uni = gw * gh + aw_ * ah_ - inter;
                float r = inter / uni;
                if (r > best) { best = r; bn = n; }
            }
            int gi = (int)gx; gi = gi < 0 ? 0 : (gi > kNW - 1 ? kNW - 1 : gi);
            int gj = (int)gy; gj = gj < 0 ? 0 : (gj > kNH - 1 ? kNH - 1 : gj);
            cell = bn * kPLANE + gj * kNW + gi;
        }
        int   cellT = __shfl(cell, t_ce & 63, 64);
        float c0T   = __shfl(c0,   t_ce & 63, 64);
        // owner = no later valid target maps to the same cell (scatter last-write-wins)
        unsigned long long dup = __ballot(t > t_ce && cell == cellT && cell >= 0);
        doCE = (t_ce < nv) && (dup == 0ull);
        if (doCE) {
            int bn = cellT >> 12, pix = cellT & (kPLANE - 1);
            int tcls = (int)c0T;
            const float* lg = out + ((size_t)(b * kNA + bn) * kCH + 5) * kPLANE + pix;
            ceV0 = lg[(size_t)lane * kPLANE];
            if (lane < kNC - 64) ceV1 = lg[(size_t)(64 + lane) * kPLANE];
            ceLt = lg[(size_t)tcls * kPLANE];
        }
    }
    __syncthreads();
    const int nv = snv;

    // ---------- Phase C: per-cell loss (o0..o4 already in registers) ----------
    float tx   = fsig(o0);
    float ty   = fsig(o1);
    float tw   = o2;
    float th   = o3;
    float conf = fsig(o4);

    float aw = anchors[2 * a], ah = anchors[2 * a + 1];
    float pw = __expf(tw) * aw, ph = __expf(th) * ah;
    float px = tx + (float)i, py = ty + (float)j;
    float px1 = px - 0.5f * pw, px2 = px + 0.5f * pw;
    float py1 = py - 0.5f * ph, py2 = py + 0.5f * ph;
    float p06 = 0.6f * pw * ph;
    int mycell = a * kPLANE + remp;

    // iou > 0.6  <=>  max_t(1.6*inter - 0.6*garea) > 0.6*parea
    float flag = -INFINITY;
    int match = -1;                                   // last matching t wins
    for (int t = 0; t < nv; ++t) {
        const float4 bx = *reinterpret_cast<const float4*>(srec + t * kRECF);
        const float2 gc = *reinterpret_cast<const float2*>(srec + t * kRECF + 4);
        float cw  = fminf(bx.y, px2) - fmaxf(bx.x, px1);
        float chh = fminf(bx.w, py2) - fmaxf(bx.z, py1);
        float inter = fmaxf(cw, 0.f) * fmaxf(chh, 0.f);
        flag = fmaxf(flag, fmaf(1.6f, inter, -gc.x));
        match = (__float_as_int(gc.y) == mycell) ? t : match;
    }

    float t0 = 0.5f, t1 = 0.5f, t2 = 0.f, t3 = 0.f, tconf = 0.f, cmask;
    if (match >= 0) {
        const float4 tt = *reinterpret_cast<const float4*>(srec + match * kRECF + 8);
        t0 = tt.x; t1 = tt.y; t2 = tt.z; t3 = tt.w;
        tconf = srec[match * kRECF + 12];
        cmask = kOBJ;
    } else {
        cmask = (flag > p06) ? 0.f : 1.f;
    }

    float dx = tx - t0, dy = ty - t1, dw = tw - t2, dh = th - t3, dc = conf - tconf;
    float loss = 0.5f * (dx * dx + dy * dy + dw * dw + dh * dh)
               + 0.5f * cmask * dc * dc;

    // ---------- Phase D: finish CE on waves 1-3 (wave-uniform per wave) ----------
    if (doCE) {
        float mx = fmaxf(ceV0, ceV1);
        #pragma unroll
        for (int off = 32; off > 0; off >>= 1) mx = fmaxf(mx, __shfl_xor(mx, off, 64));
        float s = __expf(ceV0 - mx) + ((lane < kNC - 64) ? __expf(ceV1 - mx) : 0.f);
        #pragma unroll
        for (int off = 32; off > 0; off >>= 1) s += __shfl_xor(s, off, 64);
        if (lane == 0) loss += __logf(s) + mx - ceLt;
    }

    // ---------- Phase E: block reduction -> one partial per block ----------
    #pragma unroll
    for (int off = 32; off > 0; off >>= 1) loss += __shfl_down(loss, off, 64);
    if (lane == 0) wred[wave] = loss;
    __syncthreads();
    if (wave == 0) {
        float v = (lane < 16) ? wred[lane] : 0.f;
        #pragma unroll
        for (int off = 8; off > 0; off >>= 1) v += __shfl_xor(v, off, 64);
        if (lane == 0) partials[blockIdx.x] = v;
    }
}

// -------------------- Kernel 2: deterministic final sum (one wave) --------------------
__global__ __launch_bounds__(64) void k_final(const float* __restrict__ partials,
                                              float* __restrict__ outv) {
    float s = 0.f;
    for (int k = threadIdx.x; k < kGRID; k += 64) s += partials[k];
    #pragma unroll
    for (int off = 32; off > 0; off >>= 1) s += __shfl_xor(s, off, 64);
    if (threadIdx.x == 0) outv[0] = s;
}

extern "C" void kernel_launch(void* const* d_in, const int* in_sizes, int n_in,
                              void* d_out, int out_size, void* d_ws, size_t ws_size,
                              hipStream_t stream) {
    const float* output  = (const float*)d_in[0];
    const float* target  = (const float*)d_in[1];
    const float* anchors = (const float*)d_in[2];

    float* partials = (float*)d_ws;                  // 320 floats

    k_fused<<<kGRID, kBLK, 0, stream>>>(output, target, anchors, partials);
    k_final<<<1, 64, 0, stream>>>(partials, (float*)d_out);
}